// Round 1
// baseline (1045.070 us; speedup 1.0000x reference)
//
#include <hip/hip_runtime.h>
#include <stdint.h>

// Problem constants
#define BATCH 32
#define H 225
#define W 225
#define CH 128          // channels
#define CG 32           // channel float4-groups = CH/4
#define PG 8            // pooled grid 8x8
#define OUTD 7          // output 7x7
#define ITERS 10

__device__ __forceinline__ float4 f4max(float4 a, float4 b) {
    return make_float4(fmaxf(a.x, b.x), fmaxf(a.y, b.y),
                       fmaxf(a.z, b.z), fmaxf(a.w, b.w));
}

// Kernel 1: SAME max-pool 225x225 -> 8x8 over NHWC, windows tile the input
// exactly once (pad_low=15 -> window i = [max(0,32i-15), min(225,32i+17)) ).
// One block per (b, i, j). tid -> (sp = tid>>5 strided over columns,
// cg = tid&31 float4 channel group). Wave reads 1KB contiguous per step.
__global__ __launch_bounds__(256)
void pool_kernel(const float4* __restrict__ x, float4* __restrict__ pooled) {
    const int bid = blockIdx.x;
    const int j = bid & 7;
    const int i = (bid >> 3) & 7;
    const int b = bid >> 6;
    const int tid = threadIdx.x;
    const int cg = tid & 31;
    const int sp = tid >> 5;

    const int rs = max(0, i * 32 - 15), re = min(H, i * 32 + 17);
    const int cs = max(0, j * 32 - 15), ce = min(W, j * 32 + 17);

    float4 acc = make_float4(-INFINITY, -INFINITY, -INFINITY, -INFINITY);
    for (int r = rs; r < re; ++r) {
        const float4* rowp = x + (size_t)(b * H + r) * (W * CG);
        for (int cl = cs + sp; cl < ce; cl += 8) {
            acc = f4max(acc, rowp[cl * CG + cg]);
        }
    }

    __shared__ float4 red[8][CG];
    red[sp][cg] = acc;
    __syncthreads();
    if (sp < 4) red[sp][cg] = f4max(red[sp][cg], red[sp + 4][cg]);
    __syncthreads();
    if (sp < 2) red[sp][cg] = f4max(red[sp][cg], red[sp + 2][cg]);
    __syncthreads();
    if (sp == 0) {
        float4 v = f4max(red[0][cg], red[1][cg]);
        pooled[((b * PG + i) * PG + j) * CG + cg] = v;
    }
}

// Kernel 2: for each of 10 iterations, merge row pair (i,i+1) and col pair
// (j,j+1) of the 8x8 pooled grid (max), map to 7x7, accumulate, /10.
// Output row r maps to pooled rows [r + (r>i), r + (r>i) + (r==i)].
__global__ __launch_bounds__(256)
void merge_kernel(const float4* __restrict__ pooled, float4* __restrict__ out,
                  uint32_t ipack, uint32_t jpack) {
    const int t = blockIdx.x * 256 + threadIdx.x;
    const int total = BATCH * OUTD * OUTD * CG;
    if (t >= total) return;
    const int cg = t & 31;
    int u = t >> 5;
    const int c = u % OUTD; u /= OUTD;
    const int r = u % OUTD;
    const int b = u / OUTD;

    const float4* pb = pooled + (size_t)b * PG * PG * CG;
    float4 sum = make_float4(0.f, 0.f, 0.f, 0.f);
    #pragma unroll
    for (int it = 0; it < ITERS; ++it) {
        const int i = (ipack >> (3 * it)) & 7;
        const int j = (jpack >> (3 * it)) & 7;
        const int r0 = r + (r > i), r1 = r0 + (r == i);
        const int c0 = c + (c > j), c1 = c0 + (c == j);
        float4 v = pb[(r0 * PG + c0) * CG + cg];
        if (c1 != c0) v = f4max(v, pb[(r0 * PG + c1) * CG + cg]);
        if (r1 != r0) {
            v = f4max(v, pb[(r1 * PG + c0) * CG + cg]);
            if (c1 != c0) v = f4max(v, pb[(r1 * PG + c1) * CG + cg]);
        }
        sum.x += v.x; sum.y += v.y; sum.z += v.z; sum.w += v.w;
    }
    out[t] = make_float4(sum.x / 10.0f, sum.y / 10.0f,
                         sum.z / 10.0f, sum.w / 10.0f);
}

// ---- Host-side replication of np.random.RandomState(seed).randint(0,7) ----
// Legacy numpy: MT19937 seeded via init_genrand(seed); randint(0,7) has
// rng = high-1-low = 6, mask = 7; for rng <= 0xffffffff the legacy masked
// path draws 32-bit values: val = next32() & 7, reject while val > 6.
namespace {
struct MT {
    uint32_t mt[624];
    int pos;
    explicit MT(uint32_t seed) {
        for (int k = 0; k < 624; ++k) {
            mt[k] = seed;
            seed = 1812433253u * (seed ^ (seed >> 30)) + (uint32_t)(k + 1);
        }
        pos = 624;
    }
    uint32_t next() {
        if (pos >= 624) {
            for (int k = 0; k < 624; ++k) {
                uint32_t y = (mt[k] & 0x80000000u) | (mt[(k + 1) % 624] & 0x7fffffffu);
                mt[k] = mt[(k + 397) % 624] ^ (y >> 1) ^ ((y & 1u) ? 2567483615u : 0u);
            }
            pos = 0;
        }
        uint32_t y = mt[pos++];
        y ^= y >> 11;
        y ^= (y << 7) & 2636928640u;
        y ^= (y << 15) & 4022730752u;
        y ^= y >> 18;
        return y;
    }
    int randint7() {  // randint(0, 7) -> [0, 6]
        uint32_t v;
        do { v = next() & 7u; } while (v > 6u);
        return (int)v;
    }
};
}  // namespace

extern "C" void kernel_launch(void* const* d_in, const int* in_sizes, int n_in,
                              void* d_out, int out_size, void* d_ws, size_t ws_size,
                              hipStream_t stream) {
    (void)in_sizes; (void)n_in; (void)out_size; (void)ws_size;
    const float4* x = (const float4*)d_in[0];
    float4* pooled = (float4*)d_ws;          // 32*8*8*128 floats = 1 MiB
    float4* out = (float4*)d_out;

    uint32_t ipack = 0, jpack = 0;
    for (int it = 0; it < ITERS; ++it) {
        MT rng((uint32_t)(42 + it));
        const int i = rng.randint7();   // row merge index (drawn first)
        const int j = rng.randint7();   // col merge index (second draw)
        ipack |= (uint32_t)i << (3 * it);
        jpack |= (uint32_t)j << (3 * it);
    }

    pool_kernel<<<dim3(BATCH * PG * PG), dim3(256), 0, stream>>>(x, pooled);

    const int total = BATCH * OUTD * OUTD * CG;  // 50176 float4s
    merge_kernel<<<dim3((total + 255) / 256), dim3(256), 0, stream>>>(
        pooled, out, ipack, jpack);
}

// Round 2
// 1034.807 us; speedup vs baseline: 1.0099x; 1.0099x over previous
//
#include <hip/hip_runtime.h>
#include <stdint.h>

// Problem constants
#define BATCH 32
#define H 225
#define W 225
#define CH 128          // channels
#define CG 32           // channel float4-groups = CH/4
#define PG 8            // pooled grid 8x8
#define OUTD 7          // output 7x7
#define ITERS 10

__device__ __forceinline__ float4 f4max(float4 a, float4 b) {
    return make_float4(fmaxf(a.x, b.x), fmaxf(a.y, b.y),
                       fmaxf(a.z, b.z), fmaxf(a.w, b.w));
}

// Kernel 1: SAME max-pool 225x225 -> 8x8 over NHWC.
// Window i covers rows [max(0,32i-15), min(225,32i+17)) — windows tile the
// input exactly once. Trick: clamping the raw index 32i-15+rr (rr in [0,32))
// to [0,224] lands exactly inside the window for every i, and max is
// idempotent, so every block runs a uniform branch-free 32x32 pattern
// (edge duplicates are same-address repeats -> L1 hits, no extra HBM).
// One block per (b,i,j); thread (sp=tid>>5, cg=tid&31) covers 4 cols x 32
// rows with 4 independent accumulators; rows unrolled x4 -> 16 loads in
// flight per thread.
__global__ __launch_bounds__(256)
void pool_kernel(const float4* __restrict__ x, float4* __restrict__ pooled) {
    const int bid = blockIdx.x;
    const int j = bid & 7;
    const int i = (bid >> 3) & 7;
    const int b = bid >> 6;
    const int tid = threadIdx.x;
    const int cg = tid & 31;
    const int sp = tid >> 5;   // 0..7

    // 4 clamped column indices for this thread (compile-time trip count).
    int col[4];
    #pragma unroll
    for (int k = 0; k < 4; ++k) {
        int c = j * 32 - 15 + sp + 8 * k;
        col[k] = min(max(c, 0), W - 1);
    }

    const float4 ninf = make_float4(-INFINITY, -INFINITY, -INFINITY, -INFINITY);
    float4 a0 = ninf, a1 = ninf, a2 = ninf, a3 = ninf;
    const int rbase = i * 32 - 15;

    #pragma unroll 4
    for (int rr = 0; rr < 32; ++rr) {
        const int r = min(max(rbase + rr, 0), H - 1);
        const float4* rowp = x + (size_t)(b * H + r) * (W * CG) + cg;
        a0 = f4max(a0, rowp[col[0] * CG]);
        a1 = f4max(a1, rowp[col[1] * CG]);
        a2 = f4max(a2, rowp[col[2] * CG]);
        a3 = f4max(a3, rowp[col[3] * CG]);
    }
    float4 acc = f4max(f4max(a0, a1), f4max(a2, a3));

    // Reduce 8 sp-partials per cg: in-wave xor-32 shuffle, then LDS across
    // the 4 waves (single __syncthreads).
    acc.x = fmaxf(acc.x, __shfl_xor(acc.x, 32));
    acc.y = fmaxf(acc.y, __shfl_xor(acc.y, 32));
    acc.z = fmaxf(acc.z, __shfl_xor(acc.z, 32));
    acc.w = fmaxf(acc.w, __shfl_xor(acc.w, 32));

    __shared__ float4 red[4][CG];
    const int wave = tid >> 6;          // 0..3
    if ((tid & 63) < 32) red[wave][cg] = acc;
    __syncthreads();
    if (tid < 32) {
        float4 v = f4max(f4max(red[0][tid], red[1][tid]),
                         f4max(red[2][tid], red[3][tid]));
        pooled[((b * PG + i) * PG + j) * CG + tid] = v;
    }
}

// Kernel 2: for each of 10 iterations, merge row pair (i,i+1) and col pair
// (j,j+1) of the 8x8 pooled grid (max), map to 7x7, accumulate, /10.
// Output row r maps to pooled rows [r + (r>i), r + (r>i) + (r==i)].
__global__ __launch_bounds__(256)
void merge_kernel(const float4* __restrict__ pooled, float4* __restrict__ out,
                  uint32_t ipack, uint32_t jpack) {
    const int t = blockIdx.x * 256 + threadIdx.x;
    const int total = BATCH * OUTD * OUTD * CG;
    if (t >= total) return;
    const int cg = t & 31;
    int u = t >> 5;
    const int c = u % OUTD; u /= OUTD;
    const int r = u % OUTD;
    const int b = u / OUTD;

    const float4* pb = pooled + (size_t)b * PG * PG * CG;
    float4 sum = make_float4(0.f, 0.f, 0.f, 0.f);
    #pragma unroll
    for (int it = 0; it < ITERS; ++it) {
        const int i = (ipack >> (3 * it)) & 7;
        const int j = (jpack >> (3 * it)) & 7;
        const int r0 = r + (r > i), r1 = r0 + (r == i);
        const int c0 = c + (c > j), c1 = c0 + (c == j);
        float4 v = pb[(r0 * PG + c0) * CG + cg];
        if (c1 != c0) v = f4max(v, pb[(r0 * PG + c1) * CG + cg]);
        if (r1 != r0) {
            v = f4max(v, pb[(r1 * PG + c0) * CG + cg]);
            if (c1 != c0) v = f4max(v, pb[(r1 * PG + c1) * CG + cg]);
        }
        sum.x += v.x; sum.y += v.y; sum.z += v.z; sum.w += v.w;
    }
    out[t] = make_float4(sum.x / 10.0f, sum.y / 10.0f,
                         sum.z / 10.0f, sum.w / 10.0f);
}

// ---- Host-side replication of np.random.RandomState(seed).randint(0,7) ----
// Legacy numpy: MT19937 seeded via init_genrand(seed); randint(0,7) has
// rng = 6, mask = 7; legacy masked path draws 32-bit values:
// val = next32() & 7, reject while val > 6.
namespace {
struct MT {
    uint32_t mt[624];
    int pos;
    explicit MT(uint32_t seed) {
        for (int k = 0; k < 624; ++k) {
            mt[k] = seed;
            seed = 1812433253u * (seed ^ (seed >> 30)) + (uint32_t)(k + 1);
        }
        pos = 624;
    }
    uint32_t next() {
        if (pos >= 624) {
            for (int k = 0; k < 624; ++k) {
                uint32_t y = (mt[k] & 0x80000000u) | (mt[(k + 1) % 624] & 0x7fffffffu);
                mt[k] = mt[(k + 397) % 624] ^ (y >> 1) ^ ((y & 1u) ? 2567483615u : 0u);
            }
            pos = 0;
        }
        uint32_t y = mt[pos++];
        y ^= y >> 11;
        y ^= (y << 7) & 2636928640u;
        y ^= (y << 15) & 4022730752u;
        y ^= y >> 18;
        return y;
    }
    int randint7() {  // randint(0, 7) -> [0, 6]
        uint32_t v;
        do { v = next() & 7u; } while (v > 6u);
        return (int)v;
    }
};
}  // namespace

extern "C" void kernel_launch(void* const* d_in, const int* in_sizes, int n_in,
                              void* d_out, int out_size, void* d_ws, size_t ws_size,
                              hipStream_t stream) {
    (void)in_sizes; (void)n_in; (void)out_size; (void)ws_size;
    const float4* x = (const float4*)d_in[0];
    float4* pooled = (float4*)d_ws;          // 32*8*8*128 floats = 1 MiB
    float4* out = (float4*)d_out;

    uint32_t ipack = 0, jpack = 0;
    for (int it = 0; it < ITERS; ++it) {
        MT rng((uint32_t)(42 + it));
        const int i = rng.randint7();   // row merge index (drawn first)
        const int j = rng.randint7();   // col merge index (second draw)
        ipack |= (uint32_t)i << (3 * it);
        jpack |= (uint32_t)j << (3 * it);
    }

    pool_kernel<<<dim3(BATCH * PG * PG), dim3(256), 0, stream>>>(x, pooled);

    const int total = BATCH * OUTD * OUTD * CG;  // 50176 float4s
    merge_kernel<<<dim3((total + 255) / 256), 256, 0, stream>>>(
        pooled, out, ipack, jpack);
}